// Round 1
// baseline (244.922 us; speedup 1.0000x reference)
//
#include <hip/hip_runtime.h>

typedef float  f32x4 __attribute__((ext_vector_type(4)));
typedef short  s16x8 __attribute__((ext_vector_type(8)));

constexpr int Bn = 4, Sn = 2048, En = 512, Hn = 8;
constexpr int BH = Bn * Hn;   // 32

static __device__ __forceinline__ ushort f2bf(float f) {
  union { float f; uint u; } v; v.f = f;
  uint r = v.u + 0x7fffu + ((v.u >> 16) & 1u);   // RNE
  return (ushort)(r >> 16);
}

// ---------------- Kernel 1: per-head projections ----------------
// grid (Sn/64, BH, 3), block 256. role 0=q,1=k (write [BH,S,64] bf16),
// role 2=v (write transposed [BH,64,S] bf16 so PV B-frag is k-contiguous).
__global__ __launch_bounds__(256) void proj_kernel(
    const float* __restrict__ Qi, const float* __restrict__ Ki, const float* __restrict__ Vi,
    const float* __restrict__ Wq, const float* __restrict__ bq,
    const float* __restrict__ Wk, const float* __restrict__ bk,
    const float* __restrict__ Wv, const float* __restrict__ bv,
    ushort* __restrict__ qo, ushort* __restrict__ ko, ushort* __restrict__ vto)
{
  __shared__ float Wt[64 * 65];          // W transposed [d][o], pad 65 -> conflict-free
  const int role = blockIdx.z;
  const float* X    = role == 0 ? Qi : (role == 1 ? Ki : Vi);
  const float* W    = role == 0 ? Wq : (role == 1 ? Wk : Wv);
  const float* bias = role == 0 ? bq : (role == 1 ? bk : bv);
  const int t = threadIdx.x;
  for (int i = t; i < 4096; i += 256)
    Wt[(i & 63) * 65 + (i >> 6)] = W[i];
  __syncthreads();
  const int lane = t & 63, w = t >> 6;
  const int bh = blockIdx.y, b = bh >> 3, h = bh & 7;
  const float bl = bias[lane];
  const int sb = blockIdx.x * 64 + w * 16;
  for (int si = 0; si < 2; ++si) {
    const int s0 = sb + si * 8;
    float x[8], acc[8];
#pragma unroll
    for (int r = 0; r < 8; ++r) {
      x[r] = X[((size_t)b * Sn + s0 + r) * En + h * 64 + lane];  // lane indexes d
      acc[r] = bl;
    }
    for (int d = 0; d < 64; ++d) {
      const float wt = Wt[d * 65 + lane];                        // lane indexes o
#pragma unroll
      for (int r = 0; r < 8; ++r)
        acc[r] = fmaf(__shfl(x[r], d), wt, acc[r]);
    }
    if (role < 2) {
      ushort* dst = role == 0 ? qo : ko;
#pragma unroll
      for (int r = 0; r < 8; ++r)
        dst[((size_t)bh * Sn + s0 + r) * 64 + lane] = f2bf(acc[r]);
    } else {
      union { ushort us[8]; uint4 u; } pk;
#pragma unroll
      for (int r = 0; r < 8; ++r) pk.us[r] = f2bf(acc[r]);
      *(uint4*)&vto[((size_t)bh * 64 + lane) * Sn + s0] = pk.u;  // vT[o][s0..s0+8]
    }
  }
}

// ---------------- Kernel 2: flash attention ----------------
// grid (Sn/64, BH), block 256 (4 waves x 16 q-rows). KBLK=64.
// mfma_f32_16x16x32_bf16: A[m][kk]: lane m=l&15, kk=(l>>4)*8+j ; B[kk][n]: n=l&15 ;
// C: col=l&15, row=(l>>4)*4+r  [guide §3, m89-verified].
// S^T[k][q] = mfma(A=K rows, B=Q rows). attn^T[d][q] = mfma(A=V^T rows, B=P rows).
__global__ __launch_bounds__(256) void flash_kernel(
    const ushort* __restrict__ q, const ushort* __restrict__ k,
    const ushort* __restrict__ vt, ushort* __restrict__ attn)
{
  constexpr int LP = 72;                 // LDS pitch (bf16): 144B -> even 8x8 bank groups
  __shared__ ushort Kl[64 * LP];         // K tile [k][d]
  __shared__ ushort Vl[64 * LP];         // V^T tile [d][k]
  __shared__ ushort Pl[64 * LP];         // per-wave P [q][k]
  const int t = threadIdx.x, lane = t & 63, w = t >> 6;
  const int g = lane >> 4, ql = lane & 15;
  const int bh = blockIdx.y;
  const int qrow = blockIdx.x * 64 + w * 16 + ql;
  const ushort* qp = q + ((size_t)bh * Sn + qrow) * 64;
  const s16x8 qf0 = *(const s16x8*)(qp + g * 8);        // d 0..31
  const s16x8 qf1 = *(const s16x8*)(qp + 32 + g * 8);   // d 32..63
  f32x4 acc[4];
#pragma unroll
  for (int i = 0; i < 4; ++i) acc[i] = (f32x4){0.f, 0.f, 0.f, 0.f};
  float mrun = -1e30f, lrun = 0.f;
  const ushort* kb = k + (size_t)bh * Sn * 64;
  const ushort* vb = vt + (size_t)bh * 64 * Sn;
  const int srow = t >> 3, sc = t & 7;

  for (int k0 = 0; k0 < Sn; k0 += 64) {
    __syncthreads();                                    // prev-iter LDS reads done
#pragma unroll
    for (int p = 0; p < 2; ++p) {
      const int rr = srow + p * 32;
      const uint4 kv = *(const uint4*)(kb + ((size_t)(k0 + rr)) * 64 + sc * 8);
      const uint4 vv = *(const uint4*)(vb + (size_t)rr * Sn + k0 + sc * 8);
      *(uint4*)&Kl[rr * LP + sc * 8] = kv;
      *(uint4*)&Vl[rr * LP + sc * 8] = vv;
    }
    __syncthreads();

    // ---- S^T = K . Q^T (scaled) ----
    f32x4 st[4];
#pragma unroll
    for (int i = 0; i < 4; ++i) {                       // k-subtile of 16
      f32x4 c4 = {0.f, 0.f, 0.f, 0.f};
      const s16x8 a0 = *(const s16x8*)&Kl[(i * 16 + ql) * LP + g * 8];
      const s16x8 a1 = *(const s16x8*)&Kl[(i * 16 + ql) * LP + 32 + g * 8];
      c4 = __builtin_amdgcn_mfma_f32_16x16x32_bf16(a0, qf0, c4, 0, 0, 0);
      c4 = __builtin_amdgcn_mfma_f32_16x16x32_bf16(a1, qf1, c4, 0, 0, 0);
      st[i] = c4 * 0.125f;                              // 1/sqrt(64)
    }
    // ---- online softmax (lane's col q = l&15; reduce over 4 lanes via xor 16/32) ----
    float tmax = st[0][0];
#pragma unroll
    for (int i = 0; i < 4; ++i)
#pragma unroll
      for (int r = 0; r < 4; ++r) tmax = fmaxf(tmax, st[i][r]);
    tmax = fmaxf(tmax, __shfl_xor(tmax, 16));
    tmax = fmaxf(tmax, __shfl_xor(tmax, 32));
    const float mnew = fmaxf(mrun, tmax);
    const float scale = __expf(mrun - mnew);
    lrun *= scale;
#pragma unroll
    for (int i = 0; i < 4; ++i)
#pragma unroll
      for (int r = 0; r < 4; ++r) acc[i][r] *= scale;
    float tsum = 0.f;
#pragma unroll
    for (int i = 0; i < 4; ++i) {
      union { ushort us[4]; uint2 u; } pk;
#pragma unroll
      for (int r = 0; r < 4; ++r) {
        const float pv = __expf(st[i][r] - mnew);
        tsum += pv;
        pk.us[r] = f2bf(pv);
      }
      // lane holds P[q][k] for k = i*16 + 4g + (0..3) -> packed 8B write
      *(uint2*)&Pl[(w * 16 + ql) * LP + i * 16 + g * 4] = pk.u;
    }
    tsum += __shfl_xor(tsum, 16);
    tsum += __shfl_xor(tsum, 32);
    lrun += tsum;
    mrun = mnew;

    // ---- attn^T += V^T . P^T ----  (Pl wave-local: no barrier needed)
#pragma unroll
    for (int dt = 0; dt < 4; ++dt) {
#pragma unroll
      for (int kc = 0; kc < 2; ++kc) {
        const s16x8 av = *(const s16x8*)&Vl[(dt * 16 + ql) * LP + kc * 32 + g * 8];
        const s16x8 bp = *(const s16x8*)&Pl[(w * 16 + ql) * LP + kc * 32 + g * 8];
        acc[dt] = __builtin_amdgcn_mfma_f32_16x16x32_bf16(av, bp, acc[dt], 0, 0, 0);
      }
    }
  }
  // ---- epilogue: attn[b,s,h,d] bf16 ----
  const float inv = 1.f / lrun;
  const int b = bh >> 3, h = bh & 7;
  ushort* ap = attn + ((size_t)(b * Sn + qrow)) * En + h * 64;
#pragma unroll
  for (int dt = 0; dt < 4; ++dt) {
    union { ushort us[4]; uint2 u; } pk;
#pragma unroll
    for (int r = 0; r < 4; ++r) pk.us[r] = f2bf(acc[dt][r] * inv);
    *(uint2*)&ap[dt * 16 + g * 4] = pk.u;               // d = dt*16 + 4g + r
  }
}

// ---------------- Kernel 3: output projection ----------------
// out[m][n] = sum_e attn[m][e] * Wo[n][e] + bo[n].  grid (8192/64, 512/64), block 256.
// D[n][m] = mfma(A=Wo rows, B=attn rows): col=m -> lane writes 4 consecutive n (float4).
__global__ __launch_bounds__(256) void outproj_kernel(
    const ushort* __restrict__ attn, const float* __restrict__ Wo,
    const float* __restrict__ bo, float* __restrict__ out)
{
  constexpr int LP = 72;
  __shared__ ushort Al[64 * LP];
  __shared__ ushort Wl[64 * LP];
  const int t = threadIdx.x, lane = t & 63, w = t >> 6;
  const int g = lane >> 4, ml = lane & 15;
  const int m0 = blockIdx.x * 64, n0 = blockIdx.y * 64;
  f32x4 acc[4];
#pragma unroll
  for (int i = 0; i < 4; ++i) acc[i] = (f32x4){0.f, 0.f, 0.f, 0.f};
  for (int e0 = 0; e0 < En; e0 += 64) {
    __syncthreads();
    {
      const int row = t >> 3, c = t & 7;
#pragma unroll
      for (int p = 0; p < 2; ++p) {
        const int rr = row + p * 32;
        const uint4 v = *(const uint4*)(attn + ((size_t)(m0 + rr)) * En + e0 + c * 8);
        *(uint4*)&Al[rr * LP + c * 8] = v;
      }
    }
    {
      const int row = t >> 4, c = t & 15;
#pragma unroll
      for (int p = 0; p < 4; ++p) {
        const int rr = row + p * 16;
        const float4 v = *(const float4*)(Wo + ((size_t)(n0 + rr)) * En + e0 + c * 4);
        union { ushort us[4]; uint2 u; } pk;
        pk.us[0] = f2bf(v.x); pk.us[1] = f2bf(v.y);
        pk.us[2] = f2bf(v.z); pk.us[3] = f2bf(v.w);
        *(uint2*)&Wl[rr * LP + c * 4] = pk.u;
      }
    }
    __syncthreads();
#pragma unroll
    for (int kc = 0; kc < 2; ++kc) {
      const s16x8 bfrag = *(const s16x8*)&Al[(w * 16 + ml) * LP + kc * 32 + g * 8];
#pragma unroll
      for (int nt = 0; nt < 4; ++nt) {
        const s16x8 afrag = *(const s16x8*)&Wl[(nt * 16 + ml) * LP + kc * 32 + g * 8];
        acc[nt] = __builtin_amdgcn_mfma_f32_16x16x32_bf16(afrag, bfrag, acc[nt], 0, 0, 0);
      }
    }
  }
  const int mrow = m0 + w * 16 + ml;
#pragma unroll
  for (int nt = 0; nt < 4; ++nt) {
    const float4 bias = *(const float4*)(bo + n0 + nt * 16 + g * 4);
    float4 o;
    o.x = acc[nt][0] + bias.x;
    o.y = acc[nt][1] + bias.y;
    o.z = acc[nt][2] + bias.z;
    o.w = acc[nt][3] + bias.w;
    *(float4*)&out[(size_t)mrow * En + n0 + nt * 16 + g * 4] = o;
  }
}

extern "C" void kernel_launch(void* const* d_in, const int* in_sizes, int n_in,
                              void* d_out, int out_size, void* d_ws, size_t ws_size,
                              hipStream_t stream) {
  const float* Qi = (const float*)d_in[0];
  const float* Ki = (const float*)d_in[1];
  const float* Vi = (const float*)d_in[2];
  const float* Wq = (const float*)d_in[3];
  const float* bq = (const float*)d_in[4];
  const float* Wk = (const float*)d_in[5];
  const float* bk = (const float*)d_in[6];
  const float* Wv = (const float*)d_in[7];
  const float* bv = (const float*)d_in[8];
  const float* Wo = (const float*)d_in[9];
  const float* bo = (const float*)d_in[10];

  const size_t TEN = (size_t)BH * Sn * 64;   // 4 Mi elems per bf16 tensor
  ushort* qw  = (ushort*)d_ws;
  ushort* kw  = qw + TEN;
  ushort* vtw = kw + TEN;
  ushort* at  = vtw + TEN;                   // total 32 MB of ws

  proj_kernel<<<dim3(Sn / 64, BH, 3), 256, 0, stream>>>(
      Qi, Ki, Vi, Wq, bq, Wk, bk, Wv, bv, qw, kw, vtw);
  flash_kernel<<<dim3(Sn / 64, BH), 256, 0, stream>>>(qw, kw, vtw, at);
  outproj_kernel<<<dim3(Bn * Sn / 64, En / 64), 256, 0, stream>>>(
      at, Wo, bo, (float*)d_out);
}

// Round 2
// 128.426 us; speedup vs baseline: 1.9071x; 1.9071x over previous
//
#include <hip/hip_runtime.h>

typedef float  f32x4 __attribute__((ext_vector_type(4)));
typedef short  s16x8 __attribute__((ext_vector_type(8)));

constexpr int Bn = 4, Sn = 2048, En = 512, Hn = 8;
constexpr int BH = Bn * Hn;   // 32

static __device__ __forceinline__ ushort f2bf(float f) {
  union { float f; uint u; } v; v.f = f;
  uint r = v.u + 0x7fffu + ((v.u >> 16) & 1u);   // RNE
  return (ushort)(r >> 16);
}

static __device__ __forceinline__ uint2 pack4(float a, float b, float c, float d) {
  union { ushort us[4]; uint2 u; } pk;
  pk.us[0] = f2bf(a); pk.us[1] = f2bf(b); pk.us[2] = f2bf(c); pk.us[3] = f2bf(d);
  return pk.u;
}

// ---------------- Kernel 1: per-head projections (MFMA) ----------------
// grid (Sn/64, BH, 3), block 256 (4 waves; wave w owns s-subtile w*16).
// D[o][s] = mfma(A=W rows [o][d], B=x rows [s][d]); C: col=s(lane&15), row o=(lane>>4)*4+r.
// role 0=q,1=k -> [BH,S,64]; role 2=v -> transposed [BH,64,S] for flash PV B-operand.
__global__ __launch_bounds__(256) void proj_kernel(
    const float* __restrict__ Qi, const float* __restrict__ Ki, const float* __restrict__ Vi,
    const float* __restrict__ Wq, const float* __restrict__ bq,
    const float* __restrict__ Wk, const float* __restrict__ bk,
    const float* __restrict__ Wv, const float* __restrict__ bv,
    ushort* __restrict__ qo, ushort* __restrict__ ko, ushort* __restrict__ vto)
{
  constexpr int LP = 72;
  __shared__ ushort Xl[64 * LP];
  __shared__ ushort Wl[64 * LP];
  const int role = blockIdx.z;
  const float* X    = role == 0 ? Qi : (role == 1 ? Ki : Vi);
  const float* W    = role == 0 ? Wq : (role == 1 ? Wk : Wv);
  const float* bias = role == 0 ? bq : (role == 1 ? bk : bv);
  const int t = threadIdx.x, lane = t & 63, w = t >> 6;
  const int g = lane >> 4, ql = lane & 15;
  const int bh = blockIdx.y, b = bh >> 3, h = bh & 7;
  const int s0 = blockIdx.x * 64;

  {
    const int row = t >> 4, c = t & 15;          // 16 threads/row, 4 floats each
#pragma unroll
    for (int p = 0; p < 4; ++p) {
      const int rr = row + p * 16;
      const float4 wv = *(const float4*)(W + rr * 64 + c * 4);
      *(uint2*)&Wl[rr * LP + c * 4] = pack4(wv.x, wv.y, wv.z, wv.w);
      const float4 xv = *(const float4*)(X + ((size_t)b * Sn + s0 + rr) * En + h * 64 + c * 4);
      *(uint2*)&Xl[rr * LP + c * 4] = pack4(xv.x, xv.y, xv.z, xv.w);
    }
  }
  __syncthreads();

  f32x4 acc[4];
#pragma unroll
  for (int i = 0; i < 4; ++i) acc[i] = (f32x4){0.f, 0.f, 0.f, 0.f};
#pragma unroll
  for (int kc = 0; kc < 2; ++kc) {
    const s16x8 bfrag = *(const s16x8*)&Xl[(w * 16 + ql) * LP + kc * 32 + g * 8];
#pragma unroll
    for (int nt = 0; nt < 4; ++nt) {
      const s16x8 afrag = *(const s16x8*)&Wl[(nt * 16 + ql) * LP + kc * 32 + g * 8];
      acc[nt] = __builtin_amdgcn_mfma_f32_16x16x32_bf16(afrag, bfrag, acc[nt], 0, 0, 0);
    }
  }

  const int s = s0 + w * 16 + ql;
  if (role < 2) {
    ushort* dst = (role == 0 ? qo : ko) + ((size_t)bh * Sn + s) * 64;
#pragma unroll
    for (int nt = 0; nt < 4; ++nt) {
      const int ob = nt * 16 + g * 4;
      *(uint2*)&dst[ob] = pack4(acc[nt][0] + bias[ob], acc[nt][1] + bias[ob + 1],
                                acc[nt][2] + bias[ob + 2], acc[nt][3] + bias[ob + 3]);
    }
  } else {
#pragma unroll
    for (int nt = 0; nt < 4; ++nt) {
#pragma unroll
      for (int r = 0; r < 4; ++r) {
        const int o = nt * 16 + g * 4 + r;
        vto[((size_t)bh * 64 + o) * Sn + s] = f2bf(acc[nt][r] + bias[o]);
      }
    }
  }
}

// ---------------- Kernel 2: flash attention ----------------
// grid (Sn/64, BH), block 256 (4 waves x 16 q-rows). KBLK=64.
// S^T[k][q] = mfma(A=K rows, B=Q rows). attn^T[d][q] = mfma(A=V^T rows, B=P rows).
__global__ __launch_bounds__(256) void flash_kernel(
    const ushort* __restrict__ q, const ushort* __restrict__ k,
    const ushort* __restrict__ vt, ushort* __restrict__ attn)
{
  constexpr int LP = 72;                 // LDS pitch (bf16): 144B -> even bank spread
  __shared__ ushort Kl[64 * LP];         // K tile [k][d]
  __shared__ ushort Vl[64 * LP];         // V^T tile [d][k]
  __shared__ ushort Pl[64 * LP];         // per-wave P [q][k]
  const int t = threadIdx.x, lane = t & 63, w = t >> 6;
  const int g = lane >> 4, ql = lane & 15;
  const int bh = blockIdx.y;
  const int qrow = blockIdx.x * 64 + w * 16 + ql;
  const ushort* qp = q + ((size_t)bh * Sn + qrow) * 64;
  const s16x8 qf0 = *(const s16x8*)(qp + g * 8);        // d 0..31
  const s16x8 qf1 = *(const s16x8*)(qp + 32 + g * 8);   // d 32..63
  f32x4 acc[4];
#pragma unroll
  for (int i = 0; i < 4; ++i) acc[i] = (f32x4){0.f, 0.f, 0.f, 0.f};
  float mrun = -1e30f, lrun = 0.f;
  const ushort* kb = k + (size_t)bh * Sn * 64;
  const ushort* vb = vt + (size_t)bh * 64 * Sn;
  const int srow = t >> 3, sc = t & 7;

  for (int k0 = 0; k0 < Sn; k0 += 64) {
    __syncthreads();                                    // prev-iter LDS reads done
#pragma unroll
    for (int p = 0; p < 2; ++p) {
      const int rr = srow + p * 32;
      const uint4 kv = *(const uint4*)(kb + ((size_t)(k0 + rr)) * 64 + sc * 8);
      const uint4 vv = *(const uint4*)(vb + (size_t)rr * Sn + k0 + sc * 8);
      *(uint4*)&Kl[rr * LP + sc * 8] = kv;
      *(uint4*)&Vl[rr * LP + sc * 8] = vv;
    }
    __syncthreads();

    // ---- S^T = K . Q^T (scaled) ----
    f32x4 st[4];
#pragma unroll
    for (int i = 0; i < 4; ++i) {                       // k-subtile of 16
      f32x4 c4 = {0.f, 0.f, 0.f, 0.f};
      const s16x8 a0 = *(const s16x8*)&Kl[(i * 16 + ql) * LP + g * 8];
      const s16x8 a1 = *(const s16x8*)&Kl[(i * 16 + ql) * LP + 32 + g * 8];
      c4 = __builtin_amdgcn_mfma_f32_16x16x32_bf16(a0, qf0, c4, 0, 0, 0);
      c4 = __builtin_amdgcn_mfma_f32_16x16x32_bf16(a1, qf1, c4, 0, 0, 0);
      st[i] = c4 * 0.125f;                              // 1/sqrt(64)
    }
    // ---- online softmax (lane's col q = l&15; reduce over 4 lanes via xor 16/32) ----
    float tmax = st[0][0];
#pragma unroll
    for (int i = 0; i < 4; ++i)
#pragma unroll
      for (int r = 0; r < 4; ++r) tmax = fmaxf(tmax, st[i][r]);
    tmax = fmaxf(tmax, __shfl_xor(tmax, 16));
    tmax = fmaxf(tmax, __shfl_xor(tmax, 32));
    const float mnew = fmaxf(mrun, tmax);
    const float scale = __expf(mrun - mnew);
    lrun *= scale;
#pragma unroll
    for (int i = 0; i < 4; ++i)
#pragma unroll
      for (int r = 0; r < 4; ++r) acc[i][r] *= scale;
    float tsum = 0.f;
#pragma unroll
    for (int i = 0; i < 4; ++i) {
      union { ushort us[4]; uint2 u; } pk;
#pragma unroll
      for (int r = 0; r < 4; ++r) {
        const float pv = __expf(st[i][r] - mnew);
        tsum += pv;
        pk.us[r] = f2bf(pv);
      }
      // lane holds P[q][k] for k = i*16 + 4g + (0..3) -> packed 8B write
      *(uint2*)&Pl[(w * 16 + ql) * LP + i * 16 + g * 4] = pk.u;
    }
    tsum += __shfl_xor(tsum, 16);
    tsum += __shfl_xor(tsum, 32);
    lrun += tsum;
    mrun = mnew;

    // ---- attn^T += V^T . P^T ----  (Pl wave-local: no barrier needed)
#pragma unroll
    for (int dt = 0; dt < 4; ++dt) {
#pragma unroll
      for (int kc = 0; kc < 2; ++kc) {
        const s16x8 av = *(const s16x8*)&Vl[(dt * 16 + ql) * LP + kc * 32 + g * 8];
        const s16x8 bp = *(const s16x8*)&Pl[(w * 16 + ql) * LP + kc * 32 + g * 8];
        acc[dt] = __builtin_amdgcn_mfma_f32_16x16x32_bf16(av, bp, acc[dt], 0, 0, 0);
      }
    }
  }
  // ---- epilogue: attn[b,s,h,d] bf16 ----
  const float inv = 1.f / lrun;
  const int b = bh >> 3, h = bh & 7;
  ushort* ap = attn + ((size_t)(b * Sn + qrow)) * En + h * 64;
#pragma unroll
  for (int dt = 0; dt < 4; ++dt) {
    union { ushort us[4]; uint2 u; } pk;
#pragma unroll
    for (int r = 0; r < 4; ++r) pk.us[r] = f2bf(acc[dt][r] * inv);
    *(uint2*)&ap[dt * 16 + g * 4] = pk.u;               // d = dt*16 + 4g + r
  }
}

// ---------------- Kernel 3: output projection ----------------
// out[m][n] = sum_e attn[m][e] * Wo[n][e] + bo[n].  grid (8192/64, 512/64), block 256.
// D[n][m] = mfma(A=Wo rows, B=attn rows): col=m -> lane writes 4 consecutive n (float4).
__global__ __launch_bounds__(256) void outproj_kernel(
    const ushort* __restrict__ attn, const float* __restrict__ Wo,
    const float* __restrict__ bo, float* __restrict__ out)
{
  constexpr int LP = 72;
  __shared__ ushort Al[64 * LP];
  __shared__ ushort Wl[64 * LP];
  const int t = threadIdx.x, lane = t & 63, w = t >> 6;
  const int g = lane >> 4, ml = lane & 15;
  const int m0 = blockIdx.x * 64, n0 = blockIdx.y * 64;
  f32x4 acc[4];
#pragma unroll
  for (int i = 0; i < 4; ++i) acc[i] = (f32x4){0.f, 0.f, 0.f, 0.f};
  for (int e0 = 0; e0 < En; e0 += 64) {
    __syncthreads();
    {
      const int row = t >> 3, c = t & 7;
#pragma unroll
      for (int p = 0; p < 2; ++p) {
        const int rr = row + p * 32;
        const uint4 v = *(const uint4*)(attn + ((size_t)(m0 + rr)) * En + e0 + c * 8);
        *(uint4*)&Al[rr * LP + c * 8] = v;
      }
    }
    {
      const int row = t >> 4, c = t & 15;
#pragma unroll
      for (int p = 0; p < 4; ++p) {
        const int rr = row + p * 16;
        const float4 v = *(const float4*)(Wo + ((size_t)(n0 + rr)) * En + e0 + c * 4);
        *(uint2*)&Wl[rr * LP + c * 4] = pack4(v.x, v.y, v.z, v.w);
      }
    }
    __syncthreads();
#pragma unroll
    for (int kc = 0; kc < 2; ++kc) {
      const s16x8 bfrag = *(const s16x8*)&Al[(w * 16 + ml) * LP + kc * 32 + g * 8];
#pragma unroll
      for (int nt = 0; nt < 4; ++nt) {
        const s16x8 afrag = *(const s16x8*)&Wl[(nt * 16 + ml) * LP + kc * 32 + g * 8];
        acc[nt] = __builtin_amdgcn_mfma_f32_16x16x32_bf16(afrag, bfrag, acc[nt], 0, 0, 0);
      }
    }
  }
  const int mrow = m0 + w * 16 + ml;
#pragma unroll
  for (int nt = 0; nt < 4; ++nt) {
    const float4 bias = *(const float4*)(bo + n0 + nt * 16 + g * 4);
    float4 o;
    o.x = acc[nt][0] + bias.x;
    o.y = acc[nt][1] + bias.y;
    o.z = acc[nt][2] + bias.z;
    o.w = acc[nt][3] + bias.w;
    *(float4*)&out[(size_t)mrow * En + n0 + nt * 16 + g * 4] = o;
  }
}

extern "C" void kernel_launch(void* const* d_in, const int* in_sizes, int n_in,
                              void* d_out, int out_size, void* d_ws, size_t ws_size,
                              hipStream_t stream) {
  const float* Qi = (const float*)d_in[0];
  const float* Ki = (const float*)d_in[1];
  const float* Vi = (const float*)d_in[2];
  const float* Wq = (const float*)d_in[3];
  const float* bq = (const float*)d_in[4];
  const float* Wk = (const float*)d_in[5];
  const float* bk = (const float*)d_in[6];
  const float* Wv = (const float*)d_in[7];
  const float* bv = (const float*)d_in[8];
  const float* Wo = (const float*)d_in[9];
  const float* bo = (const float*)d_in[10];

  const size_t TEN = (size_t)BH * Sn * 64;   // 4 Mi elems per bf16 tensor
  ushort* qw  = (ushort*)d_ws;
  ushort* kw  = qw + TEN;
  ushort* vtw = kw + TEN;
  ushort* at  = vtw + TEN;                   // total 32 MB of ws

  proj_kernel<<<dim3(Sn / 64, BH, 3), 256, 0, stream>>>(
      Qi, Ki, Vi, Wq, bq, Wk, bk, Wv, bv, qw, kw, vtw);
  flash_kernel<<<dim3(Sn / 64, BH), 256, 0, stream>>>(qw, kw, vtw, at);
  outproj_kernel<<<dim3(Bn * Sn / 64, En / 64), 256, 0, stream>>>(
      at, Wo, bo, (float*)d_out);
}

// Round 3
// 98.116 us; speedup vs baseline: 2.4962x; 1.3089x over previous
//
#include <hip/hip_runtime.h>

typedef float  f32x4  __attribute__((ext_vector_type(4)));
typedef float  f32x16 __attribute__((ext_vector_type(16)));
typedef short  s16x8  __attribute__((ext_vector_type(8)));

constexpr int Bn = 4, Sn = 2048, En = 512, Hn = 8;
constexpr int BH = Bn * Hn;   // 32
constexpr int NT = Sn / 64;   // 32 kv tiles
constexpr float QSCL = 0.125f * 1.44269504088896f;  // 1/sqrt(64) * log2(e), folded into q

static __device__ __forceinline__ ushort f2bf(float f) {
  union { float f; uint u; } v; v.f = f;
  uint r = v.u + 0x7fffu + ((v.u >> 16) & 1u);   // RNE
  return (ushort)(r >> 16);
}
static __device__ __forceinline__ uint2 pack4(float a, float b, float c, float d) {
  union { ushort us[4]; uint2 u; } pk;
  pk.us[0] = f2bf(a); pk.us[1] = f2bf(b); pk.us[2] = f2bf(c); pk.us[3] = f2bf(d);
  return pk.u;
}
static __device__ __forceinline__ float hexp2(float x) {
  float r; asm("v_exp_f32 %0, %1" : "=v"(r) : "v"(x)); return r;
}
static __device__ __forceinline__ uint pkbf(float lo, float hi2) {
  uint r; asm("v_cvt_pk_bf16_f32 %0, %1, %2" : "=v"(r) : "v"(lo), "v"(hi2)); return r;
}
#define SWAP32(a, b) asm("v_permlane32_swap_b32 %0, %1" : "+v"(a), "+v"(b))
static __device__ __forceinline__ s16x8 mk8(uint a, uint b, uint c, uint d) {
  union { uint u[4]; s16x8 v; } x; x.u[0] = a; x.u[1] = b; x.u[2] = c; x.u[3] = d; return x.v;
}
static __device__ __forceinline__ float vmax16(f32x16 v) {
  float a = fmaxf(fmaxf(v[0], v[1]), fmaxf(v[2], v[3]));
  float b = fmaxf(fmaxf(v[4], v[5]), fmaxf(v[6], v[7]));
  float c = fmaxf(fmaxf(v[8], v[9]), fmaxf(v[10], v[11]));
  float d = fmaxf(fmaxf(v[12], v[13]), fmaxf(v[14], v[15]));
  return fmaxf(fmaxf(a, b), fmaxf(c, d));
}
#define MFMA32(A, B, C) __builtin_amdgcn_mfma_f32_32x32x16_bf16((A), (B), (C), 0, 0, 0)
#define GLDS(SRC, DST) __builtin_amdgcn_global_load_lds( \
    (const __attribute__((address_space(1))) void*)(SRC), \
    (__attribute__((address_space(3))) void*)(DST), 16, 0, 0)

// ---------------- Kernel 1: per-head projections (MFMA 16x16x32) ----------------
// grid (Sn/64, BH, 3), block 256. role 0=q (pre-scaled by QSCL), 1=k -> [BH,S,64];
// role 2=v -> transposed [BH,64,S].
__global__ __launch_bounds__(256) void proj_kernel(
    const float* __restrict__ Qi, const float* __restrict__ Ki, const float* __restrict__ Vi,
    const float* __restrict__ Wq, const float* __restrict__ bq,
    const float* __restrict__ Wk, const float* __restrict__ bk,
    const float* __restrict__ Wv, const float* __restrict__ bv,
    ushort* __restrict__ qo, ushort* __restrict__ ko, ushort* __restrict__ vto)
{
  constexpr int LP = 72;
  __shared__ ushort Xl[64 * LP];
  __shared__ ushort Wl[64 * LP];
  const int role = blockIdx.z;
  const float* X    = role == 0 ? Qi : (role == 1 ? Ki : Vi);
  const float* W    = role == 0 ? Wq : (role == 1 ? Wk : Wv);
  const float* bias = role == 0 ? bq : (role == 1 ? bk : bv);
  const float oscl  = role == 0 ? QSCL : 1.0f;
  const int t = threadIdx.x, lane = t & 63, w = t >> 6;
  const int g = lane >> 4, ql = lane & 15;
  const int bh = blockIdx.y, b = bh >> 3, h = bh & 7;
  const int s0 = blockIdx.x * 64;

  {
    const int row = t >> 4, c = t & 15;
#pragma unroll
    for (int p = 0; p < 4; ++p) {
      const int rr = row + p * 16;
      const float4 wv = *(const float4*)(W + rr * 64 + c * 4);
      *(uint2*)&Wl[rr * LP + c * 4] = pack4(wv.x, wv.y, wv.z, wv.w);
      const float4 xv = *(const float4*)(X + ((size_t)b * Sn + s0 + rr) * En + h * 64 + c * 4);
      *(uint2*)&Xl[rr * LP + c * 4] = pack4(xv.x, xv.y, xv.z, xv.w);
    }
  }
  __syncthreads();

  f32x4 acc[4];
#pragma unroll
  for (int i = 0; i < 4; ++i) acc[i] = (f32x4){0.f, 0.f, 0.f, 0.f};
#pragma unroll
  for (int kc = 0; kc < 2; ++kc) {
    const s16x8 bfrag = *(const s16x8*)&Xl[(w * 16 + ql) * LP + kc * 32 + g * 8];
#pragma unroll
    for (int nt = 0; nt < 4; ++nt) {
      const s16x8 afrag = *(const s16x8*)&Wl[(nt * 16 + ql) * LP + kc * 32 + g * 8];
      acc[nt] = __builtin_amdgcn_mfma_f32_16x16x32_bf16(afrag, bfrag, acc[nt], 0, 0, 0);
    }
  }

  const int s = s0 + w * 16 + ql;
  if (role < 2) {
    ushort* dst = (role == 0 ? qo : ko) + ((size_t)bh * Sn + s) * 64;
#pragma unroll
    for (int nt = 0; nt < 4; ++nt) {
      const int ob = nt * 16 + g * 4;
      *(uint2*)&dst[ob] = pack4((acc[nt][0] + bias[ob]) * oscl, (acc[nt][1] + bias[ob + 1]) * oscl,
                                (acc[nt][2] + bias[ob + 2]) * oscl, (acc[nt][3] + bias[ob + 3]) * oscl);
    }
  } else {
#pragma unroll
    for (int nt = 0; nt < 4; ++nt) {
#pragma unroll
      for (int r = 0; r < 4; ++r) {
        const int o = nt * 16 + g * 4 + r;
        vto[((size_t)bh * 64 + o) * Sn + s] = f2bf(acc[nt][r] + bias[o]);
      }
    }
  }
}

// ---------------- Kernel 2: flash attention, 32x32x16 MFMA ----------------
// grid (16, 32) remapped; block 256 = 4 waves x 32 q-rows (128 q/block), KVBLK=64.
// Swapped ops: S^T[k][q] = mfma(A=K, B=Q); attn^T[d][q] = mfma(A=V^T, B=P).
// A/B frag: row(lane&31), k=(lane>>5)*8+j. C/D: col=lane&31, row=(r&3)+8(r>>2)+4(lane>>5).
// K/V staged via global_load_lds (linear LDS) with XOR-swizzled source chunks;
// reads XOR back -> conflict-free ds_read_b128 (T2, rule 21).
__global__ __launch_bounds__(256, 2) void flash_kernel(
    const ushort* __restrict__ q, const ushort* __restrict__ k,
    const ushort* __restrict__ vt, ushort* __restrict__ attn)
{
  __shared__ ushort Kl[2][4096];   // [buf][64 rows x 64 d] linear (swizzled content)
  __shared__ ushort Vl[2][4096];   // [buf][64 d-rows x 64 k]
  const int tid = threadIdx.x, lane = tid & 63, w = tid >> 6;
  const int m = lane & 31, hi = lane >> 5;
  const int hx = hi ^ (lane & 7);            // read-side chunk XOR

  int lid = blockIdx.x + (blockIdx.y << 4);  // 0..511
  lid = (lid & 7) * 64 + (lid >> 3);         // bijective XCD swizzle: 4 heads per XCD
  const int bq = lid & 15, bh = lid >> 4;
  const int qrow = bq * 128 + w * 32 + m;
  const int b = bh >> 3, h = bh & 7;

  // Q fragments (q pre-scaled by QSCL in proj)
  const ushort* qp = q + ((size_t)bh * Sn + qrow) * 64 + hi * 8;
  const s16x8 qf0 = *(const s16x8*)(qp + 0);
  const s16x8 qf1 = *(const s16x8*)(qp + 16);
  const s16x8 qf2 = *(const s16x8*)(qp + 32);
  const s16x8 qf3 = *(const s16x8*)(qp + 48);

  // staging: wave w fills rows [w*16, w*16+16) of each 64-row tile; 16B/lane/issue
  const int lr = lane >> 3, swz = (lane & 7) ^ lr;
  const int r0 = w * 16 + lr, r1 = r0 + 8;
  const ushort* kS0 = k  + (size_t)bh * Sn * 64 + (size_t)r0 * 64 + swz * 8;
  const ushort* kS1 = k  + (size_t)bh * Sn * 64 + (size_t)r1 * 64 + swz * 8;
  const ushort* vS0 = vt + ((size_t)bh * 64 + r0) * Sn + swz * 8;
  const ushort* vS1 = vt + ((size_t)bh * 64 + r1) * Sn + swz * 8;
  const uint dO0 = (uint)(w * 2048 + lane * 16), dO1 = dO0 + 1024;
  char* KB0 = (char*)&Kl[0][0]; char* KB1 = (char*)&Kl[1][0];
  char* VB0 = (char*)&Vl[0][0]; char* VB1 = (char*)&Vl[1][0];

  const f32x16 z16 = {};
  f32x16 acc0 = {}, acc1 = {}, asum = {};
  float mrun = -1e30f;
  union { ushort us[8]; s16x8 v; } onesU;
#pragma unroll
  for (int i = 0; i < 8; ++i) onesU.us[i] = 0x3F80;   // bf16 1.0
  const s16x8 ones = onesU.v;

  // prologue: stage tile 0 -> buf 0
  GLDS(kS0, KB0 + dO0); GLDS(kS1, KB0 + dO1);
  GLDS(vS0, VB0 + dO0); GLDS(vS1, VB0 + dO1);
  kS0 += 4096; kS1 += 4096; vS0 += 64; vS1 += 64;

#define LDK(BUF, KT, S) (*(const s16x8*)&Kl[BUF][((KT) * 32 + m) * 64 + (((2 * (S)) ^ hx) << 3)])
#define LDV(BUF, DT, S) (*(const s16x8*)&Vl[BUF][((DT) * 32 + m) * 64 + (((2 * (S)) ^ hx) << 3)])

#define STEP(T, BUF, KBn, VBn) do {                                         \
    if ((T) < NT - 1) {                                                     \
      GLDS(kS0, (KBn) + dO0); GLDS(kS1, (KBn) + dO1);                       \
      GLDS(vS0, (VBn) + dO0); GLDS(vS1, (VBn) + dO1);                       \
      kS0 += 4096; kS1 += 4096; vS0 += 64; vS1 += 64;                       \
      asm volatile("s_waitcnt vmcnt(4)" ::: "memory");                      \
    } else {                                                                \
      asm volatile("s_waitcnt vmcnt(0)" ::: "memory");                      \
    }                                                                       \
    __builtin_amdgcn_s_barrier();                                           \
    __builtin_amdgcn_sched_barrier(0);                                      \
    f32x16 st0, st1;                                                        \
    __builtin_amdgcn_s_setprio(1);                                          \
    st0 = MFMA32(LDK(BUF, 0, 0), qf0, z16);                                 \
    st0 = MFMA32(LDK(BUF, 0, 1), qf1, st0);                                 \
    st0 = MFMA32(LDK(BUF, 0, 2), qf2, st0);                                 \
    st0 = MFMA32(LDK(BUF, 0, 3), qf3, st0);                                 \
    st1 = MFMA32(LDK(BUF, 1, 0), qf0, z16);                                 \
    st1 = MFMA32(LDK(BUF, 1, 1), qf1, st1);                                 \
    st1 = MFMA32(LDK(BUF, 1, 2), qf2, st1);                                 \
    st1 = MFMA32(LDK(BUF, 1, 3), qf3, st1);                                 \
    __builtin_amdgcn_s_setprio(0);                                          \
    float tmax = fmaxf(vmax16(st0), vmax16(st1));                           \
    tmax = fmaxf(tmax, __shfl_xor(tmax, 32));                               \
    if (__any(tmax > mrun + 8.0f)) {                                        \
      const float mnew = fmaxf(mrun, tmax);                                 \
      const float rs = hexp2(mrun - mnew);                                  \
      mrun = mnew;                                                          \
      _Pragma("unroll")                                                     \
      for (int i = 0; i < 16; ++i) {                                        \
        acc0[i] *= rs; acc1[i] *= rs; asum[i] *= rs;                        \
      }                                                                     \
    }                                                                       \
    f32x16 p0, p1;                                                          \
    _Pragma("unroll")                                                       \
    for (int i = 0; i < 16; ++i) {                                          \
      p0[i] = hexp2(st0[i] - mrun);                                         \
      p1[i] = hexp2(st1[i] - mrun);                                         \
    }                                                                       \
    uint uA, uB, uC, uD, uE, uF, uG, uH;                                    \
    uA = pkbf(p0[0], p0[1]);  uB = pkbf(p0[4], p0[5]);   SWAP32(uA, uB);    \
    uC = pkbf(p0[2], p0[3]);  uD = pkbf(p0[6], p0[7]);   SWAP32(uC, uD);    \
    uE = pkbf(p0[8], p0[9]);  uF = pkbf(p0[12], p0[13]); SWAP32(uE, uF);    \
    uG = pkbf(p0[10], p0[11]); uH = pkbf(p0[14], p0[15]); SWAP32(uG, uH);   \
    const s16x8 pb0 = mk8(uA, uC, uB, uD);                                  \
    const s16x8 pb1 = mk8(uE, uG, uF, uH);                                  \
    uA = pkbf(p1[0], p1[1]);  uB = pkbf(p1[4], p1[5]);   SWAP32(uA, uB);    \
    uC = pkbf(p1[2], p1[3]);  uD = pkbf(p1[6], p1[7]);   SWAP32(uC, uD);    \
    uE = pkbf(p1[8], p1[9]);  uF = pkbf(p1[12], p1[13]); SWAP32(uE, uF);    \
    uG = pkbf(p1[10], p1[11]); uH = pkbf(p1[14], p1[15]); SWAP32(uG, uH);   \
    const s16x8 pb2 = mk8(uA, uC, uB, uD);                                  \
    const s16x8 pb3 = mk8(uE, uG, uF, uH);                                  \
    __builtin_amdgcn_s_setprio(1);                                          \
    acc0 = MFMA32(LDV(BUF, 0, 0), pb0, acc0);                               \
    acc0 = MFMA32(LDV(BUF, 0, 1), pb1, acc0);                               \
    acc0 = MFMA32(LDV(BUF, 0, 2), pb2, acc0);                               \
    acc0 = MFMA32(LDV(BUF, 0, 3), pb3, acc0);                               \
    acc1 = MFMA32(LDV(BUF, 1, 0), pb0, acc1);                               \
    acc1 = MFMA32(LDV(BUF, 1, 1), pb1, acc1);                               \
    acc1 = MFMA32(LDV(BUF, 1, 2), pb2, acc1);                               \
    acc1 = MFMA32(LDV(BUF, 1, 3), pb3, acc1);                               \
    asum = MFMA32(ones, pb0, asum);                                         \
    asum = MFMA32(ones, pb1, asum);                                         \
    asum = MFMA32(ones, pb2, asum);                                         \
    asum = MFMA32(ones, pb3, asum);                                         \
    __builtin_amdgcn_s_setprio(0);                                          \
    __builtin_amdgcn_s_barrier();                                           \
    __builtin_amdgcn_sched_barrier(0);                                      \
  } while (0)

  for (int T = 0; T < NT; T += 2) {
    STEP(T, 0, KB1, VB1);
    STEP(T + 1, 1, KB0, VB0);
  }

  // epilogue: attn[b, qrow, h*64 + d] bf16; lane holds col q=m, rows d
  const float inv = 1.0f / asum[0];
  ushort* ap = attn + ((size_t)(b * Sn + qrow)) * En + h * 64;
#pragma unroll
  for (int g2 = 0; g2 < 4; ++g2) {
    uint2 u0, u1;
    u0.x = pkbf(acc0[g2 * 4 + 0] * inv, acc0[g2 * 4 + 1] * inv);
    u0.y = pkbf(acc0[g2 * 4 + 2] * inv, acc0[g2 * 4 + 3] * inv);
    u1.x = pkbf(acc1[g2 * 4 + 0] * inv, acc1[g2 * 4 + 1] * inv);
    u1.y = pkbf(acc1[g2 * 4 + 2] * inv, acc1[g2 * 4 + 3] * inv);
    *(uint2*)&ap[g2 * 8 + hi * 4]      = u0;   // d = g2*8 + 4*hi + 0..3
    *(uint2*)&ap[32 + g2 * 8 + hi * 4] = u1;   // d = 32 + ...
  }
}

// ---------------- Kernel 3: output projection (unchanged) ----------------
__global__ __launch_bounds__(256) void outproj_kernel(
    const ushort* __restrict__ attn, const float* __restrict__ Wo,
    const float* __restrict__ bo, float* __restrict__ out)
{
  constexpr int LP = 72;
  __shared__ ushort Al[64 * LP];
  __shared__ ushort Wl[64 * LP];
  const int t = threadIdx.x, lane = t & 63, w = t >> 6;
  const int g = lane >> 4, ml = lane & 15;
  const int m0 = blockIdx.x * 64, n0 = blockIdx.y * 64;
  f32x4 acc[4];
#pragma unroll
  for (int i = 0; i < 4; ++i) acc[i] = (f32x4){0.f, 0.f, 0.f, 0.f};
  for (int e0 = 0; e0 < En; e0 += 64) {
    __syncthreads();
    {
      const int row = t >> 3, c = t & 7;
#pragma unroll
      for (int p = 0; p < 2; ++p) {
        const int rr = row + p * 32;
        const uint4 v = *(const uint4*)(attn + ((size_t)(m0 + rr)) * En + e0 + c * 8);
        *(uint4*)&Al[rr * LP + c * 8] = v;
      }
    }
    {
      const int row = t >> 4, c = t & 15;
#pragma unroll
      for (int p = 0; p < 4; ++p) {
        const int rr = row + p * 16;
        const float4 v = *(const float4*)(Wo + ((size_t)(n0 + rr)) * En + e0 + c * 4);
        *(uint2*)&Wl[rr * LP + c * 4] = pack4(v.x, v.y, v.z, v.w);
      }
    }
    __syncthreads();
#pragma unroll
    for (int kc = 0; kc < 2; ++kc) {
      const s16x8 bfrag = *(const s16x8*)&Al[(w * 16 + ml) * LP + kc * 32 + g * 8];
#pragma unroll
      for (int nt = 0; nt < 4; ++nt) {
        const s16x8 afrag = *(const s16x8*)&Wl[(nt * 16 + ml) * LP + kc * 32 + g * 8];
        acc[nt] = __builtin_amdgcn_mfma_f32_16x16x32_bf16(afrag, bfrag, acc[nt], 0, 0, 0);
      }
    }
  }
  const int mrow = m0 + w * 16 + ml;
#pragma unroll
  for (int nt = 0; nt < 4; ++nt) {
    const float4 bias = *(const float4*)(bo + n0 + nt * 16 + g * 4);
    float4 o;
    o.x = acc[nt][0] + bias.x;
    o.y = acc[nt][1] + bias.y;
    o.z = acc[nt][2] + bias.z;
    o.w = acc[nt][3] + bias.w;
    *(float4*)&out[(size_t)mrow * En + n0 + nt * 16 + g * 4] = o;
  }
}

extern "C" void kernel_launch(void* const* d_in, const int* in_sizes, int n_in,
                              void* d_out, int out_size, void* d_ws, size_t ws_size,
                              hipStream_t stream) {
  const float* Qi = (const float*)d_in[0];
  const float* Ki = (const float*)d_in[1];
  const float* Vi = (const float*)d_in[2];
  const float* Wq = (const float*)d_in[3];
  const float* bq = (const float*)d_in[4];
  const float* Wk = (const float*)d_in[5];
  const float* bk = (const float*)d_in[6];
  const float* Wv = (const float*)d_in[7];
  const float* bv = (const float*)d_in[8];
  const float* Wo = (const float*)d_in[9];
  const float* bo = (const float*)d_in[10];

  const size_t TEN = (size_t)BH * Sn * 64;   // 4 Mi elems per bf16 tensor
  ushort* qw  = (ushort*)d_ws;
  ushort* kw  = qw + TEN;
  ushort* vtw = kw + TEN;
  ushort* at  = vtw + TEN;                   // total 32 MB of ws

  proj_kernel<<<dim3(Sn / 64, BH, 3), 256, 0, stream>>>(
      Qi, Ki, Vi, Wq, bq, Wk, bk, Wv, bv, qw, kw, vtw);
  flash_kernel<<<dim3(16, 32), 256, 0, stream>>>(qw, kw, vtw, at);
  outproj_kernel<<<dim3(Bn * Sn / 64, En / 64), 256, 0, stream>>>(
      at, Wo, bo, (float*)d_out);
}

// Round 4
// 92.480 us; speedup vs baseline: 2.6484x; 1.0609x over previous
//
#include <hip/hip_runtime.h>

typedef float  f32x4  __attribute__((ext_vector_type(4)));
typedef float  f32x16 __attribute__((ext_vector_type(16)));
typedef short  s16x8  __attribute__((ext_vector_type(8)));

constexpr int Bn = 4, Sn = 2048, En = 512, Hn = 8;
constexpr int BH = Bn * Hn;   // 32
constexpr int NT = Sn / 64;   // 32 kv tiles
constexpr float QSCL = 0.125f * 1.44269504088896f;  // 1/sqrt(64) * log2(e), folded into q

static __device__ __forceinline__ ushort f2bf(float f) {
  union { float f; uint u; } v; v.f = f;
  uint r = v.u + 0x7fffu + ((v.u >> 16) & 1u);   // RNE
  return (ushort)(r >> 16);
}
static __device__ __forceinline__ uint2 pack4(float a, float b, float c, float d) {
  union { ushort us[4]; uint2 u; } pk;
  pk.us[0] = f2bf(a); pk.us[1] = f2bf(b); pk.us[2] = f2bf(c); pk.us[3] = f2bf(d);
  return pk.u;
}
static __device__ __forceinline__ float hexp2(float x) {
  float r; asm("v_exp_f32 %0, %1" : "=v"(r) : "v"(x)); return r;
}
static __device__ __forceinline__ uint pkbf(float lo, float hi2) {
  uint r; asm("v_cvt_pk_bf16_f32 %0, %1, %2" : "=v"(r) : "v"(lo), "v"(hi2)); return r;
}
#define SWAP32(a, b) asm("v_permlane32_swap_b32 %0, %1" : "+v"(a), "+v"(b))
static __device__ __forceinline__ s16x8 mk8(uint a, uint b, uint c, uint d) {
  union { uint u[4]; s16x8 v; } x; x.u[0] = a; x.u[1] = b; x.u[2] = c; x.u[3] = d; return x.v;
}
static __device__ __forceinline__ float vmax16(f32x16 v) {
  float a = fmaxf(fmaxf(v[0], v[1]), fmaxf(v[2], v[3]));
  float b = fmaxf(fmaxf(v[4], v[5]), fmaxf(v[6], v[7]));
  float c = fmaxf(fmaxf(v[8], v[9]), fmaxf(v[10], v[11]));
  float d = fmaxf(fmaxf(v[12], v[13]), fmaxf(v[14], v[15]));
  return fmaxf(fmaxf(a, b), fmaxf(c, d));
}
#define MFMA32(A, B, C) __builtin_amdgcn_mfma_f32_32x32x16_bf16((A), (B), (C), 0, 0, 0)
#define GLDS(SRC, DST) __builtin_amdgcn_global_load_lds( \
    (const __attribute__((address_space(1))) void*)(SRC), \
    (__attribute__((address_space(3))) void*)(DST), 16, 0, 0)

// ---------------- Kernel 1: per-head projections (MFMA 16x16x32) ----------------
// grid (Sn/64, BH, 3), block 256. role 0=q (pre-scaled by QSCL), 1=k -> [BH,S,64];
// role 2=v -> transposed [BH,64,S].
__global__ __launch_bounds__(256) void proj_kernel(
    const float* __restrict__ Qi, const float* __restrict__ Ki, const float* __restrict__ Vi,
    const float* __restrict__ Wq, const float* __restrict__ bq,
    const float* __restrict__ Wk, const float* __restrict__ bk,
    const float* __restrict__ Wv, const float* __restrict__ bv,
    ushort* __restrict__ qo, ushort* __restrict__ ko, ushort* __restrict__ vto)
{
  constexpr int LP = 72;
  __shared__ ushort Xl[64 * LP];
  __shared__ ushort Wl[64 * LP];
  const int role = blockIdx.z;
  const float* X    = role == 0 ? Qi : (role == 1 ? Ki : Vi);
  const float* W    = role == 0 ? Wq : (role == 1 ? Wk : Wv);
  const float* bias = role == 0 ? bq : (role == 1 ? bk : bv);
  const float oscl  = role == 0 ? QSCL : 1.0f;
  const int t = threadIdx.x, lane = t & 63, w = t >> 6;
  const int g = lane >> 4, ql = lane & 15;
  const int bh = blockIdx.y, b = bh >> 3, h = bh & 7;
  const int s0 = blockIdx.x * 64;

  {
    const int row = t >> 4, c = t & 15;
#pragma unroll
    for (int p = 0; p < 4; ++p) {
      const int rr = row + p * 16;
      const float4 wv = *(const float4*)(W + rr * 64 + c * 4);
      *(uint2*)&Wl[rr * LP + c * 4] = pack4(wv.x, wv.y, wv.z, wv.w);
      const float4 xv = *(const float4*)(X + ((size_t)b * Sn + s0 + rr) * En + h * 64 + c * 4);
      *(uint2*)&Xl[rr * LP + c * 4] = pack4(xv.x, xv.y, xv.z, xv.w);
    }
  }
  __syncthreads();

  f32x4 acc[4];
#pragma unroll
  for (int i = 0; i < 4; ++i) acc[i] = (f32x4){0.f, 0.f, 0.f, 0.f};
#pragma unroll
  for (int kc = 0; kc < 2; ++kc) {
    const s16x8 bfrag = *(const s16x8*)&Xl[(w * 16 + ql) * LP + kc * 32 + g * 8];
#pragma unroll
    for (int nt = 0; nt < 4; ++nt) {
      const s16x8 afrag = *(const s16x8*)&Wl[(nt * 16 + ql) * LP + kc * 32 + g * 8];
      acc[nt] = __builtin_amdgcn_mfma_f32_16x16x32_bf16(afrag, bfrag, acc[nt], 0, 0, 0);
    }
  }

  const int s = s0 + w * 16 + ql;
  if (role < 2) {
    ushort* dst = (role == 0 ? qo : ko) + ((size_t)bh * Sn + s) * 64;
#pragma unroll
    for (int nt = 0; nt < 4; ++nt) {
      const int ob = nt * 16 + g * 4;
      *(uint2*)&dst[ob] = pack4((acc[nt][0] + bias[ob]) * oscl, (acc[nt][1] + bias[ob + 1]) * oscl,
                                (acc[nt][2] + bias[ob + 2]) * oscl, (acc[nt][3] + bias[ob + 3]) * oscl);
    }
  } else {
#pragma unroll
    for (int nt = 0; nt < 4; ++nt) {
#pragma unroll
      for (int r = 0; r < 4; ++r) {
        const int o = nt * 16 + g * 4 + r;
        vto[((size_t)bh * 64 + o) * Sn + s] = f2bf(acc[nt][r] + bias[o]);
      }
    }
  }
}

// ---------------- Kernel 2: flash attention, 32x32x16, in-block KV-split ----------------
// grid (16, 32) remapped; block 512 = 8 waves. Wave pair (w, w+4): same 32 q-cols
// (col-tile w&3), k-halves 0/1 of each 64-row KV tile; private (m,l,acc); merged
// via LDS at the epilogue. Swapped ops: S^T[k][q]=mfma(K,Q); attn^T[d][q]=mfma(V^T,P).
__global__ __launch_bounds__(512, 4) void flash_kernel(
    const ushort* __restrict__ q, const ushort* __restrict__ k,
    const ushort* __restrict__ vt, ushort* __restrict__ attn)
{
  __shared__ __align__(16) char smem[36864];      // K0|K1|V0|V1 (8KB each) / merge area
  float* mrg = (float*)smem;
  const int tid = threadIdx.x, lane = tid & 63, w = tid >> 6;
  const int m = lane & 31, hi = lane >> 5;
  const int wl = w & 3, h2 = w >> 2;              // col-tile, k-half
  const int hx  = hi ^ (lane & 7);                // K read chunk XOR
  const int hxv = hx ^ (h2 << 2);                 // V read chunk XOR (k-half offset folded)

  int lid = blockIdx.x + (blockIdx.y << 4);       // 0..511
  lid = (lid & 7) * 64 + (lid >> 3);              // bijective XCD swizzle
  const int bq = lid & 15, bh = lid >> 4;
  const int qrow = bq * 128 + wl * 32 + m;
  const int b = bh >> 3, h = bh & 7;

  // Q fragments (pre-scaled by QSCL in proj)
  const ushort* qp = q + ((size_t)bh * Sn + qrow) * 64 + hi * 8;
  const s16x8 qf0 = *(const s16x8*)(qp + 0);
  const s16x8 qf1 = *(const s16x8*)(qp + 16);
  const s16x8 qf2 = *(const s16x8*)(qp + 32);
  const s16x8 qf3 = *(const s16x8*)(qp + 48);

  // staging: 512 threads, thread t covers row t>>3, 16B chunk t&7 (XOR-swizzled src)
  const int srow = tid >> 3, sc = tid & 7, scs = sc ^ (srow & 7);
  const ushort* kS = k  + (size_t)bh * Sn * 64 + (size_t)srow * 64 + scs * 8;
  const ushort* vS = vt + ((size_t)bh * 64 + srow) * Sn + scs * 8;
  const uint dO = (uint)(tid * 16);
  char* KB0 = smem;          char* KB1 = smem + 8192;
  char* VB0 = smem + 16384;  char* VB1 = smem + 24576;

  const f32x16 z16 = {};
  f32x16 acc0 = {}, acc1 = {};
  float mrun = -1e30f, lsum = 0.f;

  // prologue: stage tile 0 -> buf 0
  GLDS(kS, KB0 + dO); GLDS(vS, VB0 + dO);
  kS += 4096; vS += 64;

#define LDK(KB, S)     (*(const s16x8*)((KB)  + ((h2 * 32 + m) * 64 + (((2 * (S)) ^ hx ) << 3)) * 2))
#define LDV(VB, DT, S) (*(const s16x8*)((VB)  + (((DT) * 32 + m) * 64 + (((2 * (S)) ^ hxv) << 3)) * 2))

#define STEP(T, KB, VB, KBn, VBn) do {                                      \
    if ((T) < NT - 1) {                                                     \
      GLDS(kS, (KBn) + dO); GLDS(vS, (VBn) + dO);                           \
      kS += 4096; vS += 64;                                                 \
      asm volatile("s_waitcnt vmcnt(2)" ::: "memory");                      \
    } else {                                                                \
      asm volatile("s_waitcnt vmcnt(0)" ::: "memory");                      \
    }                                                                       \
    __builtin_amdgcn_s_barrier();                                           \
    __builtin_amdgcn_sched_barrier(0);                                      \
    f32x16 st;                                                              \
    __builtin_amdgcn_s_setprio(1);                                          \
    st = MFMA32(LDK(KB, 0), qf0, z16);                                      \
    st = MFMA32(LDK(KB, 1), qf1, st);                                       \
    st = MFMA32(LDK(KB, 2), qf2, st);                                       \
    st = MFMA32(LDK(KB, 3), qf3, st);                                       \
    __builtin_amdgcn_s_setprio(0);                                          \
    float tmax = vmax16(st);                                                \
    tmax = fmaxf(tmax, __shfl_xor(tmax, 32));                               \
    if (__any(tmax > mrun + 8.0f)) {                                        \
      const float mnew = fmaxf(mrun, tmax);                                 \
      const float rs = hexp2(mrun - mnew);                                  \
      mrun = mnew; lsum *= rs;                                              \
      _Pragma("unroll")                                                     \
      for (int i = 0; i < 16; ++i) { acc0[i] *= rs; acc1[i] *= rs; }        \
    }                                                                       \
    f32x16 p;                                                               \
    _Pragma("unroll")                                                       \
    for (int i = 0; i < 16; ++i) { p[i] = hexp2(st[i] - mrun); lsum += p[i]; } \
    uint uA, uB, uC, uD, uE, uF, uG, uH;                                    \
    uA = pkbf(p[0], p[1]);   uB = pkbf(p[4], p[5]);   SWAP32(uA, uB);       \
    uC = pkbf(p[2], p[3]);   uD = pkbf(p[6], p[7]);   SWAP32(uC, uD);       \
    uE = pkbf(p[8], p[9]);   uF = pkbf(p[12], p[13]); SWAP32(uE, uF);       \
    uG = pkbf(p[10], p[11]); uH = pkbf(p[14], p[15]); SWAP32(uG, uH);       \
    const s16x8 pb0 = mk8(uA, uC, uB, uD);                                  \
    const s16x8 pb1 = mk8(uE, uG, uF, uH);                                  \
    __builtin_amdgcn_s_setprio(1);                                          \
    acc0 = MFMA32(LDV(VB, 0, 0), pb0, acc0);                                \
    acc0 = MFMA32(LDV(VB, 0, 1), pb1, acc0);                                \
    acc1 = MFMA32(LDV(VB, 1, 0), pb0, acc1);                                \
    acc1 = MFMA32(LDV(VB, 1, 1), pb1, acc1);                                \
    __builtin_amdgcn_s_setprio(0);                                          \
    __builtin_amdgcn_s_barrier();                                           \
    __builtin_amdgcn_sched_barrier(0);                                      \
  } while (0)

  for (int T = 0; T < NT; T += 2) {
    STEP(T,     KB0, VB0, KB1, VB1);
    STEP(T + 1, KB1, VB1, KB0, VB0);
  }
#undef STEP
#undef LDK
#undef LDV

  // ---- epilogue: merge k-half partials (pair w <-> w+4), lower wave writes out ----
  const float lT = lsum + __shfl_xor(lsum, 32);       // row-sum over this k-half
  float* mp = mrg + (size_t)(wl * 64 + lane) * 36;    // 36-f32 stride, 16B aligned
  __syncthreads();                                    // drain LDS reads before overwrite
  if (h2) {
#pragma unroll
    for (int i = 0; i < 4; ++i) {
      f32x4 t0 = {acc0[4 * i], acc0[4 * i + 1], acc0[4 * i + 2], acc0[4 * i + 3]};
      f32x4 t1 = {acc1[4 * i], acc1[4 * i + 1], acc1[4 * i + 2], acc1[4 * i + 3]};
      *(f32x4*)(mp + 4 * i) = t0;
      *(f32x4*)(mp + 16 + 4 * i) = t1;
    }
    mp[32] = mrun; mp[33] = lT;
  }
  __syncthreads();
  if (!h2) {
    const float mU = mp[32], lU = mp[33];
    const float mM = fmaxf(mrun, mU);
    const float rL = hexp2(mrun - mM), rU = hexp2(mU - mM);
    const float inv = 1.0f / (lT * rL + lU * rU);
    const float sL = rL * inv, sU = rU * inv;
    ushort* ap = attn + ((size_t)(b * Sn + qrow)) * En + h * 64;
#pragma unroll
    for (int g2 = 0; g2 < 4; ++g2) {
      float a0 = acc0[g2 * 4 + 0] * sL + mp[g2 * 4 + 0] * sU;
      float a1 = acc0[g2 * 4 + 1] * sL + mp[g2 * 4 + 1] * sU;
      float a2 = acc0[g2 * 4 + 2] * sL + mp[g2 * 4 + 2] * sU;
      float a3 = acc0[g2 * 4 + 3] * sL + mp[g2 * 4 + 3] * sU;
      float c0 = acc1[g2 * 4 + 0] * sL + mp[16 + g2 * 4 + 0] * sU;
      float c1 = acc1[g2 * 4 + 1] * sL + mp[16 + g2 * 4 + 1] * sU;
      float c2 = acc1[g2 * 4 + 2] * sL + mp[16 + g2 * 4 + 2] * sU;
      float c3 = acc1[g2 * 4 + 3] * sL + mp[16 + g2 * 4 + 3] * sU;
      uint2 u0, u1;
      u0.x = pkbf(a0, a1); u0.y = pkbf(a2, a3);
      u1.x = pkbf(c0, c1); u1.y = pkbf(c2, c3);
      *(uint2*)&ap[g2 * 8 + hi * 4]      = u0;   // d = g2*8 + 4*hi + 0..3
      *(uint2*)&ap[32 + g2 * 8 + hi * 4] = u1;   // d = 32 + ...
    }
  }
}

// ---------------- Kernel 3: output projection (unchanged) ----------------
__global__ __launch_bounds__(256) void outproj_kernel(
    const ushort* __restrict__ attn, const float* __restrict__ Wo,
    const float* __restrict__ bo, float* __restrict__ out)
{
  constexpr int LP = 72;
  __shared__ ushort Al[64 * LP];
  __shared__ ushort Wl[64 * LP];
  const int t = threadIdx.x, lane = t & 63, w = t >> 6;
  const int g = lane >> 4, ml = lane & 15;
  const int m0 = blockIdx.x * 64, n0 = blockIdx.y * 64;
  f32x4 acc[4];
#pragma unroll
  for (int i = 0; i < 4; ++i) acc[i] = (f32x4){0.f, 0.f, 0.f, 0.f};
  for (int e0 = 0; e0 < En; e0 += 64) {
    __syncthreads();
    {
      const int row = t >> 3, c = t & 7;
#pragma unroll
      for (int p = 0; p < 2; ++p) {
        const int rr = row + p * 32;
        const uint4 v = *(const uint4*)(attn + ((size_t)(m0 + rr)) * En + e0 + c * 8);
        *(uint4*)&Al[rr * LP + c * 8] = v;
      }
    }
    {
      const int row = t >> 4, c = t & 15;
#pragma unroll
      for (int p = 0; p < 4; ++p) {
        const int rr = row + p * 16;
        const float4 v = *(const float4*)(Wo + ((size_t)(n0 + rr)) * En + e0 + c * 4);
        *(uint2*)&Wl[rr * LP + c * 4] = pack4(v.x, v.y, v.z, v.w);
      }
    }
    __syncthreads();
#pragma unroll
    for (int kc = 0; kc < 2; ++kc) {
      const s16x8 bfrag = *(const s16x8*)&Al[(w * 16 + ml) * LP + kc * 32 + g * 8];
#pragma unroll
      for (int nt = 0; nt < 4; ++nt) {
        const s16x8 afrag = *(const s16x8*)&Wl[(nt * 16 + ml) * LP + kc * 32 + g * 8];
        acc[nt] = __builtin_amdgcn_mfma_f32_16x16x32_bf16(afrag, bfrag, acc[nt], 0, 0, 0);
      }
    }
  }
  const int mrow = m0 + w * 16 + ml;
#pragma unroll
  for (int nt = 0; nt < 4; ++nt) {
    const float4 bias = *(const float4*)(bo + n0 + nt * 16 + g * 4);
    float4 o;
    o.x = acc[nt][0] + bias.x;
    o.y = acc[nt][1] + bias.y;
    o.z = acc[nt][2] + bias.z;
    o.w = acc[nt][3] + bias.w;
    *(float4*)&out[(size_t)mrow * En + n0 + nt * 16 + g * 4] = o;
  }
}

extern "C" void kernel_launch(void* const* d_in, const int* in_sizes, int n_in,
                              void* d_out, int out_size, void* d_ws, size_t ws_size,
                              hipStream_t stream) {
  const float* Qi = (const float*)d_in[0];
  const float* Ki = (const float*)d_in[1];
  const float* Vi = (const float*)d_in[2];
  const float* Wq = (const float*)d_in[3];
  const float* bq = (const float*)d_in[4];
  const float* Wk = (const float*)d_in[5];
  const float* bk = (const float*)d_in[6];
  const float* Wv = (const float*)d_in[7];
  const float* bv = (const float*)d_in[8];
  const float* Wo = (const float*)d_in[9];
  const float* bo = (const float*)d_in[10];

  const size_t TEN = (size_t)BH * Sn * 64;   // 4 Mi elems per bf16 tensor
  ushort* qw  = (ushort*)d_ws;
  ushort* kw  = qw + TEN;
  ushort* vtw = kw + TEN;
  ushort* at  = vtw + TEN;                   // total 32 MB of ws

  proj_kernel<<<dim3(Sn / 64, BH, 3), 256, 0, stream>>>(
      Qi, Ki, Vi, Wq, bq, Wk, bk, Wv, bv, qw, kw, vtw);
  flash_kernel<<<dim3(16, 32), 512, 0, stream>>>(qw, kw, vtw, at);
  outproj_kernel<<<dim3(Bn * Sn / 64, En / 64), 256, 0, stream>>>(
      at, Wo, bo, (float*)d_out);
}